// Round 7
// baseline (261.212 us; speedup 1.0000x reference)
//
#include <hip/hip_runtime.h>

typedef __bf16 bf16;
typedef __bf16 bf16x8 __attribute__((ext_vector_type(8)));
typedef float f32x4 __attribute__((ext_vector_type(4)));

#define EPS 1e-8f

constexpr int B = 16, CI = 256, CO = 256, S = 512, H = 64, W = 64;
constexpr int PH = 66;                    // padded spatial dim
constexpr int TAPS = 9;                   // 3x3

// 16-byte "chunks" (8 bf16):
//   wd   chunks: [tap][ci8=32][co=256]    -> UNMODULATED shared weights, 1.18 MB
//   xpad chunks: [b][row=66][ci8=32][col=66] -> style-scaled input, 35.7 MB
constexpr size_t WS_WD    = 0;                            // 1,179,648 B
constexpr size_t WS_XPAD  = 1179648;
constexpr size_t WS_INV   = WS_XPAD + (size_t)B*PH*32*PH*16;  // [B][CO] f32 = 16 KB

// ----------------------------------------------------------------- prep ----
// ROUND 12: ONE dependency-free prep kernel (grid 8720), replacing
// prep1+prep2.  R10 (hand barrier) hung; R11 (hipLaunchCooperativeKernel)
// silently no-op'd under graph capture (absmax == max|ref| -> out never
// written).  Grid-wide sync is unusable in this harness -> get the fusion
// win WITHOUT cross-block deps:
//   - style is recomputed inline where needed (xpad blocks: 8 dot-512 via
//     32-lane groups; invstd blocks: one style per thread) — a few us of
//     redundant L2-hot reads instead of a kernel boundary.
//   - invstd computes sum_tap w^2 directly from wts rows (f32x4, aligned).
//   - XCD-MATCH: blocks producing xpad for sample b run on XCD b>>1 — the
//     same XCD that convolves b (conv: b = (blk&7)*2+..).  R4's prep2 had
//     writer XCD = ci8%8 vs reader XCD = b/2: guaranteed cross-XCD miss.
//     If the kernel-boundary flush is writeback-only, conv's xpad reads
//     become local-L2 hits (diagnostic: conv FETCH_SIZE 26 MB -> <12 MB).
//   - heavy low-count blocks (wd 256, invstd 16) FIRST (272 = 0 mod 8
//     keeps the xpad XCD mapping) so they overlap xpad instead of tailing.
// block map: [0,256) wd-prep | [256,272) invstd | [272,8464) xpad main |
//            [8464,8720) borders
__global__ __launch_bounds__(256) void prep_kernel(
        const float* __restrict__ x,
        const float* __restrict__ y,
        const float* __restrict__ wts,
        const float* __restrict__ sw,
        const float* __restrict__ sb,
        bf16x8* __restrict__ wd,
        bf16x8* __restrict__ xp,
        float* __restrict__ invstd) {
    __shared__ float t[8 * 289];   // wd tile / style bcast / st2
    int i = blockIdx.x;
    int tid = threadIdx.x;

    if (i < 256) {                 // ---- wd-prep: 8co x 32ci tile ----
        int cb = i & 31;           // co block (8 co each)
        int ib = i >> 5;           // ci block (32 ci each)
        const float* src = wts + ((size_t)cb * 8) * (CI * TAPS) + ib * 32 * TAPS;
        for (int e = tid; e < 8 * 288; e += 256) {
            int col = e / 288, idx = e - col * 288;        // col = co_l
            t[col * 289 + idx] = src[(size_t)col * (CI * TAPS) + idx];
        }
        __syncthreads();
        for (int c = tid; c < 288; c += 256) {
            int co_l = c & 7, ci8_l = (c >> 3) & 3, tap = c >> 5;
            bf16x8 v;
#pragma unroll
            for (int j = 0; j < 8; ++j) v[j] = (bf16)t[co_l * 289 + (ci8_l * 8 + j) * 9 + tap];
            wd[((size_t)tap * 32 + ib * 4 + ci8_l) * CO + cb * 8 + co_l] = v;
        }
        return;
    }
    if (i < 272) {                 // ---- invstd: one block per sample ----
        int idx = i - 256;         // XCD-matched: b on XCD b>>1
        int b = (idx & 7) * 2 + (idx >> 3);
        int co = tid;
        // style[b][co] inline (each thread its own sw row, f32x4)
        const float* yr = y + (size_t)b * S;
        const float* wr = sw + (size_t)co * S;
        float sacc = 0.f;
#pragma unroll 4
        for (int k = 0; k < S; k += 4) {
            f32x4 yv = *(const f32x4*)(yr + k);
            f32x4 wv = *(const f32x4*)(wr + k);
            sacc += yv[0] * wv[0] + yv[1] * wv[1] + yv[2] * wv[2] + yv[3] * wv[3];
        }
        float stv = sacc + sb[co];
        t[co] = stv * stv;
        __syncthreads();
        // sum_ci st2[ci] * sum_tap wts[co][ci][tap]^2  (row scan, 16B-aligned
        // f32x4: 4 ci = 36 floats = 9 vecs; all indices compile-time)
        const float* wrow = wts + (size_t)co * (CI * TAPS);
        float acc = 0.f;
#pragma unroll 1
        for (int ci = 0; ci < CI; ci += 4) {
            f32x4 p[9];
#pragma unroll
            for (int v4 = 0; v4 < 9; ++v4)
                p[v4] = *(const f32x4*)(wrow + ci * 9 + v4 * 4);
#pragma unroll
            for (int cc = 0; cc < 4; ++cc) {
                float ws = 0.f;
#pragma unroll
                for (int tp = 0; tp < 9; ++tp) {
                    int e = cc * 9 + tp;
                    float wv2 = p[e >> 2][e & 3];
                    ws += wv2 * wv2;
                }
                acc += ws * t[ci + cc];
            }
        }
        invstd[b * CO + co] = rsqrtf(acc + EPS);
        return;
    }
    if (i < 8464) {                // ---- xpad main (XCD-matched) ----
        int u = i - 272;           // 272 % 8 == 0 -> XCD = u & 7
        int xcd = u & 7, q = u >> 3;
        int b = xcd * 2 + (q >> 9);
        int w = q & 511;
        int ci8 = w & 31, rowgrp = w >> 5;
        int row = rowgrp * 4 + (tid >> 6), col = tid & 63;
        // inline style for c = ci8*8 .. +7: 8 x 32-lane-group dot products
        int g = tid >> 5, gl = tid & 31;
        {
            const float* yr = y + (size_t)b * S;
            const float* wr = sw + (size_t)(ci8 * 8 + g) * S;
            float sacc = 0.f;
#pragma unroll
            for (int k2 = 0; k2 < 16; ++k2) sacc += yr[gl + k2 * 32] * wr[gl + k2 * 32];
#pragma unroll
            for (int off = 16; off; off >>= 1) sacc += __shfl_down(sacc, off, 32);
            if (gl == 0) t[g] = sacc + sb[ci8 * 8 + g];
        }
        __syncthreads();
        float st_l[8];
#pragma unroll
        for (int j = 0; j < 8; ++j) st_l[j] = t[j];
        const float* xb = x + (((size_t)b * CI + ci8 * 8) * H + row) * W + col;
        bf16x8 v;
#pragma unroll
        for (int jj = 0; jj < 8; ++jj)
            v[jj] = (bf16)(__builtin_nontemporal_load(xb + (size_t)jj * H * W) * st_l[jj]);
        xp[(((size_t)b * PH + row + 1) * 32 + ci8) * PH + col + 1] = v;
        return;
    }
    // ---- borders (XCD-matched): rows {0,65} full + cols {0,65} ----
    {
        int v2 = i - 8464;         // 8464 % 8 == 0
        int xcd = v2 & 7, j = v2 >> 3;         // j 0..31
        int b = xcd * 2 + (j >> 4), part = j & 15;
        bf16x8 z;
#pragma unroll
        for (int jj = 0; jj < 8; ++jj) z[jj] = (bf16)0.f;
        for (int tt = tid; tt < 520; tt += 256) {
            int idx = part * 520 + tt;
            int row, ci8, col;
            if (idx < 4224) {                  // rows 0 and 65, all 66 cols
                int rowsel = idx / 2112;
                int rem = idx - rowsel * 2112;
                row = rowsel ? (PH - 1) : 0;
                ci8 = rem / 66;
                col = rem - ci8 * 66;
            } else {                           // cols 0 and 65, rows 1..64
                int j2 = idx - 4224;
                int colsel = j2 >> 11;
                int rem = j2 & 2047;
                row = 1 + (rem >> 5);
                ci8 = rem & 31;
                col = colsel ? (PH - 1) : 0;
            }
            xp[(((size_t)b * PH + row) * 32 + ci8) * PH + col] = z;
        }
    }
}

// ----------------------------------------------------------------- conv ----
// BYTE-IDENTICAL to round 4's verified 74us kernel (1-deep register
// double-buffer + sched_barrier pinning + setprio; (256,2); grid 512,
// XCD-pinned b = (blk&7)*2 + ..).
#define LOAD_TAP(c8_, kh_, kw_, av_, bv_)                                         \
    {                                                                             \
        const bf16x8* wq_ = wbase + ((size_t)((kh_)*3 + (kw_)) * 32 + (c8_)) * CO;\
        const bf16x8* xq_ = xbase + ((size_t)(kh_) * 32 * PH + (size_t)(c8_) * PH + (kw_)); \
        _Pragma("unroll") for (int a_ = 0; a_ < 4; ++a_) (av_)[a_] = wq_[a_ * 16];\
        _Pragma("unroll") for (int jr_ = 0; jr_ < 2; ++jr_)                       \
            _Pragma("unroll") for (int jc_ = 0; jc_ < 4; ++jc_)                   \
                (bv_)[jr_ * 4 + jc_] = xq_[(size_t)jr_ * 32 * PH + jc_ * 16];     \
    }

#define MFMA_STEP(av_, bv_)                                                       \
    __builtin_amdgcn_s_setprio(1);                                                \
    _Pragma("unroll") for (int a_ = 0; a_ < 4; ++a_)                              \
        _Pragma("unroll") for (int j_ = 0; j_ < 8; ++j_)                          \
            acc[a_][j_] = __builtin_amdgcn_mfma_f32_16x16x32_bf16(                \
                (av_)[a_], (bv_)[j_], acc[a_][j_], 0, 0, 0);                      \
    __builtin_amdgcn_s_setprio(0);

__global__ __launch_bounds__(256, 2) void conv_kernel(
                            const bf16x8* __restrict__ wd,
                            const bf16x8* __restrict__ xp,
                            const float* __restrict__ bias,
                            const float* __restrict__ invstd,
                            float* __restrict__ out) {
    int i = blockIdx.x;
    int xcd = i & 7, tq = i >> 3;              // tq: 0..63
    int b = xcd * 2 + (tq >> 5);               // 2 samples per XCD
    int rest = tq & 31;
    int cotile = rest & 1, rowquad = rest >> 1;
    int tid = threadIdx.x;
    int wave = tid >> 6, lane = tid & 63;
    int co_half = wave & 1, sp_half = wave >> 1;
    int r0 = rowquad * 4 + sp_half * 2;
    int co_base = cotile * 128 + co_half * 64;
    int lm = lane & 15, lk = lane >> 4;

    f32x4 acc[4][8] = {};

    const bf16x8* xpb = xp + (size_t)b * PH * 32 * PH;
    const bf16x8* wbase = wd + (size_t)lk * CO + co_base + lm;
    const bf16x8* xbase = xpb + ((size_t)r0 * 32 + lk) * PH + lm;

    bf16x8 av0[4], bv0[8], av1[4], bv1[8];

    LOAD_TAP(0, 0, 0, av0, bv0);

#pragma unroll 1
    for (int c8a = 0; c8a < 32; c8a += 8) {
#pragma unroll
        for (int v = 0; v < 18; ++v) {
            const int ntap = (v + 1) % 9;
            const int nkh = ntap / 3, nkw = ntap % 3;
            int nc8 = (v == 17) ? ((c8a + 8) & 31)
                                : (c8a + ((v + 1) / 9) * 4);
            if ((v & 1) == 0) {
                LOAD_TAP(nc8, nkh, nkw, av1, bv1);
                __builtin_amdgcn_sched_barrier(0);
                MFMA_STEP(av0, bv0);
            } else {
                LOAD_TAP(nc8, nkh, nkw, av0, bv0);
                __builtin_amdgcn_sched_barrier(0);
                MFMA_STEP(av1, bv1);
            }
        }
    }

#pragma unroll
    for (int a = 0; a < 4; ++a) {
#pragma unroll
        for (int g = 0; g < 4; ++g) {
            int co = co_base + a * 16 + lk * 4 + g;
            float sc = invstd[b * CO + co];
            float bvl = bias[co];
#pragma unroll
            for (int jr = 0; jr < 2; ++jr) {
                size_t o = (((size_t)b * CO + co) * H + r0 + jr) * W;
#pragma unroll
                for (int jc = 0; jc < 4; ++jc)
                    out[o + jc * 16 + lm] = acc[a][jr * 4 + jc][g] * sc + bvl;
            }
        }
    }
}

// --------------------------------------------------------------- launch ----
extern "C" void kernel_launch(void* const* d_in, const int* in_sizes, int n_in,
                              void* d_out, int out_size, void* d_ws, size_t ws_size,
                              hipStream_t stream) {
    const float* x    = (const float*)d_in[0];
    const float* y    = (const float*)d_in[1];
    const float* wts  = (const float*)d_in[2];
    const float* bias = (const float*)d_in[3];
    const float* sw   = (const float*)d_in[4];
    const float* sb   = (const float*)d_in[5];
    float* out = (float*)d_out;

    char* ws = (char*)d_ws;
    bf16x8* wd    = (bf16x8*)(ws + WS_WD);
    bf16x8* xpad  = (bf16x8*)(ws + WS_XPAD);
    float* invstd = (float*)(ws + WS_INV);

    prep_kernel<<<dim3(8720), dim3(256), 0, stream>>>(x, y, wts, sw, sb, wd, xpad, invstd);
    conv_kernel<<<dim3(512), dim3(256), 0, stream>>>(wd, xpad, bias, invstd, out);
}

// Round 10
// 260.410 us; speedup vs baseline: 1.0031x; 1.0031x over previous
//
#include <hip/hip_runtime.h>

typedef __bf16 bf16;
typedef __bf16 bf16x8 __attribute__((ext_vector_type(8)));
typedef float f32x4 __attribute__((ext_vector_type(4)));

#define EPS 1e-8f

constexpr int B = 16, CI = 256, CO = 256, S = 512, H = 64, W = 64;
constexpr int PH = 66;                    // padded spatial dim
constexpr int TAPS = 9;                   // 3x3

// 16-byte "chunks" (8 bf16):
//   wd   chunks: [tap][ci8=32][co=256]    -> UNMODULATED shared weights, 1.18 MB
//   xpad chunks: [b][row=66][ci8=32][col=66] -> style-scaled input, 35.7 MB
constexpr size_t WS_WD    = 0;                            // 1,179,648 B
constexpr size_t WS_XPAD  = 1179648;
constexpr size_t WS_INV   = WS_XPAD + (size_t)B*PH*32*PH*16;  // [B][CO] f32 = 16 KB

// ----------------------------------------------------------------- prep ----
// ROUND 15 = ROUND 13 science, DEFENSIVELY PERTURBED binary.  R13 source
// failed "container failed twice" twice; third audit still finds no hang /
// OOB / divergent-barrier mechanism (all three __syncthreads sites
// unconditional; all index paths bounded; f32x4 casts 16B-aligned).  To
// avoid a third identical-binary submission: removed the only exotic
// instruction in the failing delta-set (__builtin_nontemporal_load -> plain
// loads; its L2-protection value was speculative).  If THIS fails too,
// next round reverts to the round-4 known-good 3-kernel baseline.
//
// Science (from R13): dependency-free prep, style AMORTIZED 16x.
// R12's mistake: style inlined into all 8192 xpad blocks -> 16x redundant
// recompute = ~270 MB of L2 reads + a 5-shuffle reduce chain per block in
// front of a 4 KB store (prep 99us at 0.87 TB/s, VALUBusy 5%).
// Fix: one xpad block per (b, ci8, 16-row quarter) = 2048 blocks; style
// computed ONCE per block, then 4 row-group iterations stream 32 KB x ->
// 64 KB xpad.
// block map: [0,256) wd-prep | [256,272) invstd | [272,2320) xpad main |
//            [2320,2576) borders.  XCD-match: xpad/border/invstd blocks for
//            sample b run on XCD b>>1, the XCD that convolves b.
__global__ __launch_bounds__(256) void prep_kernel(
        const float* __restrict__ x,
        const float* __restrict__ y,
        const float* __restrict__ wts,
        const float* __restrict__ sw,
        const float* __restrict__ sb,
        bf16x8* __restrict__ wd,
        bf16x8* __restrict__ xp,
        float* __restrict__ invstd) {
    __shared__ float t[8 * 289];   // wd tile / style bcast / st2
    int i = blockIdx.x;
    int tid = threadIdx.x;

    if (i < 256) {                 // ---- wd-prep: 8co x 32ci tile ----
        int cb = i & 31;           // co block (8 co each)
        int ib = i >> 5;           // ci block (32 ci each)
        const float* src = wts + ((size_t)cb * 8) * (CI * TAPS) + ib * 32 * TAPS;
        for (int e = tid; e < 8 * 288; e += 256) {
            int col = e / 288, idx = e - col * 288;        // col = co_l
            t[col * 289 + idx] = src[(size_t)col * (CI * TAPS) + idx];
        }
        __syncthreads();
        for (int c = tid; c < 288; c += 256) {
            int co_l = c & 7, ci8_l = (c >> 3) & 3, tap = c >> 5;
            bf16x8 v;
#pragma unroll
            for (int j = 0; j < 8; ++j) v[j] = (bf16)t[co_l * 289 + (ci8_l * 8 + j) * 9 + tap];
            wd[((size_t)tap * 32 + ib * 4 + ci8_l) * CO + cb * 8 + co_l] = v;
        }
        return;
    }
    if (i < 272) {                 // ---- invstd: one block per sample ----
        int idx = i - 256;         // XCD-matched: b on XCD b>>1
        int b = (idx & 7) * 2 + (idx >> 3);
        int co = tid;
        // style[b][co] inline (each thread its own sw row, f32x4)
        const float* yr = y + (size_t)b * S;
        const float* wr = sw + (size_t)co * S;
        float sacc = 0.f;
#pragma unroll 4
        for (int k = 0; k < S; k += 4) {
            f32x4 yv = *(const f32x4*)(yr + k);
            f32x4 wv = *(const f32x4*)(wr + k);
            sacc += yv[0] * wv[0] + yv[1] * wv[1] + yv[2] * wv[2] + yv[3] * wv[3];
        }
        float stv = sacc + sb[co];
        t[co] = stv * stv;
        __syncthreads();
        // sum_ci st2[ci] * sum_tap wts[co][ci][tap]^2  (row scan, 16B-aligned
        // f32x4: 4 ci = 36 floats = 9 vecs; all indices compile-time)
        const float* wrow = wts + (size_t)co * (CI * TAPS);
        float acc = 0.f;
#pragma unroll 1
        for (int ci = 0; ci < CI; ci += 4) {
            f32x4 p[9];
#pragma unroll
            for (int v4 = 0; v4 < 9; ++v4)
                p[v4] = *(const f32x4*)(wrow + ci * 9 + v4 * 4);
#pragma unroll
            for (int cc = 0; cc < 4; ++cc) {
                float ws = 0.f;
#pragma unroll
                for (int tp = 0; tp < 9; ++tp) {
                    int e = cc * 9 + tp;
                    float wv2 = p[e >> 2][e & 3];
                    ws += wv2 * wv2;
                }
                acc += ws * t[ci + cc];
            }
        }
        invstd[b * CO + co] = rsqrtf(acc + EPS);
        return;
    }
    if (i < 2320) {                // ---- xpad main (XCD-matched, amortized) ----
        int u = i - 272;           // 272 % 8 == 0 -> XCD = u & 7
        int xcd = u & 7, q = u >> 3;           // q: 0..255
        int b = xcd * 2 + (q >> 7);
        int rem = q & 127;
        int ci8 = rem & 31, quarter = rem >> 5;  // quarter: 16 rows
        // inline style for c = ci8*8 .. +7: 8 x 32-lane-group dot products,
        // computed ONCE per block (amortized over 16 rows)
        int g = tid >> 5, gl = tid & 31;
        {
            const float* yr = y + (size_t)b * S;
            const float* wr = sw + (size_t)(ci8 * 8 + g) * S;
            float sacc = 0.f;
#pragma unroll
            for (int k2 = 0; k2 < 16; ++k2) sacc += yr[gl + k2 * 32] * wr[gl + k2 * 32];
#pragma unroll
            for (int off = 16; off; off >>= 1) sacc += __shfl_down(sacc, off, 32);
            if (gl == 0) t[g] = sacc + sb[ci8 * 8 + g];
        }
        __syncthreads();
        float st_l[8];
#pragma unroll
        for (int j = 0; j < 8; ++j) st_l[j] = t[j];
        int col = tid & 63;
#pragma unroll
        for (int uu = 0; uu < 4; ++uu) {
            int row = quarter * 16 + uu * 4 + (tid >> 6);
            const float* xb = x + (((size_t)b * CI + ci8 * 8) * H + row) * W + col;
            bf16x8 v;
#pragma unroll
            for (int jj = 0; jj < 8; ++jj)
                v[jj] = (bf16)(xb[(size_t)jj * H * W] * st_l[jj]);
            xp[(((size_t)b * PH + row + 1) * 32 + ci8) * PH + col + 1] = v;
        }
        return;
    }
    // ---- borders (XCD-matched): rows {0,65} full + cols {0,65} ----
    {
        int v2 = i - 2320;         // 2320 % 8 == 0
        int xcd = v2 & 7, j = v2 >> 3;         // j 0..31
        int b = xcd * 2 + (j >> 4), part = j & 15;
        bf16x8 z;
#pragma unroll
        for (int jj = 0; jj < 8; ++jj) z[jj] = (bf16)0.f;
        for (int tt = tid; tt < 520; tt += 256) {
            int idx = part * 520 + tt;
            int row, ci8, col;
            if (idx < 4224) {                  // rows 0 and 65, all 66 cols
                int rowsel = idx / 2112;
                int rem = idx - rowsel * 2112;
                row = rowsel ? (PH - 1) : 0;
                ci8 = rem / 66;
                col = rem - ci8 * 66;
            } else {                           // cols 0 and 65, rows 1..64
                int j2 = idx - 4224;
                int colsel = j2 >> 11;
                int rem = j2 & 2047;
                row = 1 + (rem >> 5);
                ci8 = rem & 31;
                col = colsel ? (PH - 1) : 0;
            }
            xp[(((size_t)b * PH + row) * 32 + ci8) * PH + col] = z;
        }
    }
}

// ----------------------------------------------------------------- conv ----
// BYTE-IDENTICAL to round 4's verified 74us kernel (1-deep register
// double-buffer + sched_barrier pinning + setprio; (256,2); grid 512,
// XCD-pinned b = (blk&7)*2 + ..).
#define LOAD_TAP(c8_, kh_, kw_, av_, bv_)                                         \
    {                                                                             \
        const bf16x8* wq_ = wbase + ((size_t)((kh_)*3 + (kw_)) * 32 + (c8_)) * CO;\
        const bf16x8* xq_ = xbase + ((size_t)(kh_) * 32 * PH + (size_t)(c8_) * PH + (kw_)); \
        _Pragma("unroll") for (int a_ = 0; a_ < 4; ++a_) (av_)[a_] = wq_[a_ * 16];\
        _Pragma("unroll") for (int jr_ = 0; jr_ < 2; ++jr_)                       \
            _Pragma("unroll") for (int jc_ = 0; jc_ < 4; ++jc_)                   \
                (bv_)[jr_ * 4 + jc_] = xq_[(size_t)jr_ * 32 * PH + jc_ * 16];     \
    }

#define MFMA_STEP(av_, bv_)                                                       \
    __builtin_amdgcn_s_setprio(1);                                                \
    _Pragma("unroll") for (int a_ = 0; a_ < 4; ++a_)                              \
        _Pragma("unroll") for (int j_ = 0; j_ < 8; ++j_)                          \
            acc[a_][j_] = __builtin_amdgcn_mfma_f32_16x16x32_bf16(                \
                (av_)[a_], (bv_)[j_], acc[a_][j_], 0, 0, 0);                      \
    __builtin_amdgcn_s_setprio(0);

__global__ __launch_bounds__(256, 2) void conv_kernel(
                            const bf16x8* __restrict__ wd,
                            const bf16x8* __restrict__ xp,
                            const float* __restrict__ bias,
                            const float* __restrict__ invstd,
                            float* __restrict__ out) {
    int i = blockIdx.x;
    int xcd = i & 7, tq = i >> 3;              // tq: 0..63
    int b = xcd * 2 + (tq >> 5);               // 2 samples per XCD
    int rest = tq & 31;
    int cotile = rest & 1, rowquad = rest >> 1;
    int tid = threadIdx.x;
    int wave = tid >> 6, lane = tid & 63;
    int co_half = wave & 1, sp_half = wave >> 1;
    int r0 = rowquad * 4 + sp_half * 2;
    int co_base = cotile * 128 + co_half * 64;
    int lm = lane & 15, lk = lane >> 4;

    f32x4 acc[4][8] = {};

    const bf16x8* xpb = xp + (size_t)b * PH * 32 * PH;
    const bf16x8* wbase = wd + (size_t)lk * CO + co_base + lm;
    const bf16x8* xbase = xpb + ((size_t)r0 * 32 + lk) * PH + lm;

    bf16x8 av0[4], bv0[8], av1[4], bv1[8];

    LOAD_TAP(0, 0, 0, av0, bv0);

#pragma unroll 1
    for (int c8a = 0; c8a < 32; c8a += 8) {
#pragma unroll
        for (int v = 0; v < 18; ++v) {
            const int ntap = (v + 1) % 9;
            const int nkh = ntap / 3, nkw = ntap % 3;
            int nc8 = (v == 17) ? ((c8a + 8) & 31)
                                : (c8a + ((v + 1) / 9) * 4);
            if ((v & 1) == 0) {
                LOAD_TAP(nc8, nkh, nkw, av1, bv1);
                __builtin_amdgcn_sched_barrier(0);
                MFMA_STEP(av0, bv0);
            } else {
                LOAD_TAP(nc8, nkh, nkw, av0, bv0);
                __builtin_amdgcn_sched_barrier(0);
                MFMA_STEP(av1, bv1);
            }
        }
    }

#pragma unroll
    for (int a = 0; a < 4; ++a) {
#pragma unroll
        for (int g = 0; g < 4; ++g) {
            int co = co_base + a * 16 + lk * 4 + g;
            float sc = invstd[b * CO + co];
            float bvl = bias[co];
#pragma unroll
            for (int jr = 0; jr < 2; ++jr) {
                size_t o = (((size_t)b * CO + co) * H + r0 + jr) * W;
#pragma unroll
                for (int jc = 0; jc < 4; ++jc)
                    out[o + jc * 16 + lm] = acc[a][jr * 4 + jc][g] * sc + bvl;
            }
        }
    }
}

// --------------------------------------------------------------- launch ----
extern "C" void kernel_launch(void* const* d_in, const int* in_sizes, int n_in,
                              void* d_out, int out_size, void* d_ws, size_t ws_size,
                              hipStream_t stream) {
    const float* x    = (const float*)d_in[0];
    const float* y    = (const float*)d_in[1];
    const float* wts  = (const float*)d_in[2];
    const float* bias = (const float*)d_in[3];
    const float* sw   = (const float*)d_in[4];
    const float* sb   = (const float*)d_in[5];
    float* out = (float*)d_out;

    char* ws = (char*)d_ws;
    bf16x8* wd    = (bf16x8*)(ws + WS_WD);
    bf16x8* xpad  = (bf16x8*)(ws + WS_XPAD);
    float* invstd = (float*)(ws + WS_INV);

    prep_kernel<<<dim3(2576), dim3(256), 0, stream>>>(x, y, wts, sw, sb, wd, xpad, invstd);
    conv_kernel<<<dim3(512), dim3(256), 0, stream>>>(wd, xpad, bias, invstd, out);
}

// Round 11
// 190.533 us; speedup vs baseline: 1.3710x; 1.3667x over previous
//
#include <hip/hip_runtime.h>

typedef __bf16 bf16;
typedef __bf16 bf16x8 __attribute__((ext_vector_type(8)));
typedef float f32x4 __attribute__((ext_vector_type(4)));

#define EPS 1e-8f

constexpr int B = 16, CI = 256, CO = 256, S = 512, H = 64, W = 64;
constexpr int PH = 66;                    // padded spatial dim
constexpr int TAPS = 9;                   // 3x3

// 16-byte "chunks" (8 bf16):
//   wd   chunks: [tap][ci8=32][co=256]    -> UNMODULATED shared weights, 1.18 MB
//   xpad chunks: [b][row=66][ci8=32][col=66] -> style-scaled input, 35.7 MB
constexpr size_t WS_WD    = 0;                            // 1,179,648 B
constexpr size_t WS_XPAD  = 1179648;
constexpr size_t WS_STYLE = WS_XPAD + (size_t)B*PH*32*PH*16;  // [B][CI] f32
constexpr size_t WS_WSQT  = WS_STYLE + 16384;             // [ci][co] f32 = 256 KB
constexpr size_t WS_INV   = WS_WSQT + 262144;             // [B][CO] f32

// ---------------------------------------------------------------- prep1 ----
// VERBATIM from rounds 0-4 (verified 5x).  blocks 0..255: wd chunks + wsqT;
// blocks 256..1279: style[b][c] = y[b]·sw[c] + sb[c].
// ROUND 16 lesson: the single-kernel "dependency-free" family (style inlined
// per block) measured 99-111us x3 with VALU 3% / BW 10% / occ 13% — a
// latency-chain prologue (y·sw dot + reduce + barrier) at the head of every
// block serializes the stream; the cheap separate style kernel was
// load-bearing.  Totals: 3-kernel 191-192 (x3) vs single-prep 260-261 (x2).
__global__ void prep1_kernel(const float* __restrict__ y,
                             const float* __restrict__ sw,
                             const float* __restrict__ sb,
                             const float* __restrict__ wts,
                             bf16x8* __restrict__ wd,
                             float* __restrict__ wsqT,
                             float* __restrict__ style) {
    __shared__ float t[8 * 289];   // stride 289: bank-conflict-free gathers
    int i = blockIdx.x;
    if (i < 256) {                 // ---- wprep: 8co x 32ci tile ----
        int cb = i & 31;           // co block 0..31 (8 co each)
        int ib = i >> 5;           // ci block 0..7  (32 ci each)
        const float* src = wts + ((size_t)cb * 8) * (CI * TAPS) + ib * 32 * TAPS;
        for (int e = threadIdx.x; e < 8 * 288; e += 256) {
            int col = e / 288, idx = e - col * 288;        // col = co_l
            t[col * 289 + idx] = src[(size_t)col * (CI * TAPS) + idx];
        }
        __syncthreads();
        // wd chunks: tap(9) x ci8_l(4) x co_l(8) = 288 (strided: 288 > 256)
        for (int c = threadIdx.x; c < 288; c += 256) {
            int co_l = c & 7, ci8_l = (c >> 3) & 3, tap = c >> 5;
            bf16x8 v;
#pragma unroll
            for (int j = 0; j < 8; ++j) v[j] = (bf16)t[co_l * 289 + (ci8_l * 8 + j) * 9 + tap];
            wd[((size_t)tap * 32 + ib * 4 + ci8_l) * CO + cb * 8 + co_l] = v;
        }
        // wsqT: ci_l(32) x co_l(8) = 256
        int c = threadIdx.x;
        int co_l = c & 7, ci_l = c >> 3;
        float s = 0.f;
#pragma unroll
        for (int tap = 0; tap < 9; ++tap) {
            float w = t[co_l * 289 + ci_l * 9 + tap];
            s += w * w;
        }
        wsqT[((size_t)(ib * 32 + ci_l)) * CO + cb * 8 + co_l] = s;
    } else {                       // ---- style: one wave per (b,c) ----
        int i2 = i - 256;
        int b = i2 >> 6;
        int c = (i2 & 63) * 4 + (threadIdx.x >> 6);
        int lane = threadIdx.x & 63;
        const float* yr = y + (size_t)b * S;
        const float* wr = sw + (size_t)c * S;
        float acc = 0.f;
#pragma unroll
        for (int k = 0; k < 8; ++k) acc += yr[lane + k * 64] * wr[lane + k * 64];
        for (int off = 32; off; off >>= 1) acc += __shfl_down(acc, off, 64);
        if (lane == 0) style[b * CI + c] = acc + sb[c];
    }
}

// ---------------------------------------------------------------- prep2 ----
// R3's verified LDS-transpose body with ONE change: 2-row tiles instead of
// 4-row.  t[4][32][65] (33 KB) capped prep2 at 4 blocks/CU = 16 waves (50%);
// t[2][32][65] (16.6 KB) -> 8 blocks/CU = 32 waves (100%), 2x block count.
// Same coalesced f32x4 loads, same bank-free gather, same chunk stores.
// block map: [0,4096) main (b, cc, rowpair) | [4096,4224) border rows 0,65 |
//            [4224,4240) invstd (8-way unrolled, verified R4).
__global__ void prep2_kernel(const float* __restrict__ x,
                             const float* __restrict__ style,
                             const float* __restrict__ wsqT,
                             bf16x8* __restrict__ xp,
                             float* __restrict__ invstd) {
    __shared__ float t[2][32][W + 1];   // 16.6 KB; stride 65: 2-way (free)
    int i = blockIdx.x;
    int tid = threadIdx.x;
    if (i >= 4224) {               // ---- invstd (16 blocks) ----
        int b = i - 4224, co = tid;
        float* tf = &t[0][0][0];
        float s = style[b * CI + co];
        tf[co] = s * s;
        __syncthreads();
        float a0 = 0.f, a1 = 0.f, a2 = 0.f, a3 = 0.f;
        float a4 = 0.f, a5 = 0.f, a6 = 0.f, a7 = 0.f;
        for (int ci = 0; ci < CI; ci += 8) {   // 8 independent load streams
            a0 += wsqT[(size_t)(ci + 0) * CO + co] * tf[ci + 0];
            a1 += wsqT[(size_t)(ci + 1) * CO + co] * tf[ci + 1];
            a2 += wsqT[(size_t)(ci + 2) * CO + co] * tf[ci + 2];
            a3 += wsqT[(size_t)(ci + 3) * CO + co] * tf[ci + 3];
            a4 += wsqT[(size_t)(ci + 4) * CO + co] * tf[ci + 4];
            a5 += wsqT[(size_t)(ci + 5) * CO + co] * tf[ci + 5];
            a6 += wsqT[(size_t)(ci + 6) * CO + co] * tf[ci + 6];
            a7 += wsqT[(size_t)(ci + 7) * CO + co] * tf[ci + 7];
        }
        float acc = ((a0 + a1) + (a2 + a3)) + ((a4 + a5) + (a6 + a7));
        invstd[b * CO + co] = rsqrtf(acc + EPS);
        return;
    }
    bf16x8 z;
#pragma unroll
    for (int j = 0; j < 8; ++j) z[j] = (bf16)0.f;

    if (i >= 4096) {               // ---- border rows 0 & 65 (128 blocks) ----
        int j2 = i - 4096;
        int cc = j2 & 7, b = j2 >> 3;
        for (int q = tid; q < 2 * 4 * PH; q += 256) {
            int row = (q >= 4 * PH) ? (PH - 1) : 0;
            int rest = (q >= 4 * PH) ? q - 4 * PH : q;
            int sub = rest / PH, col = rest - sub * PH;
            xp[(((size_t)b * PH + row) * 32 + cc * 4 + sub) * PH + col] = z;
        }
        return;
    }
    // ---- xpad main: (b, cc, rowpair) ----
    int cc = i & 7;                // ci chunk of 32 -> writer XCD = cc (as R3/R4)
    int u = i >> 3;                // 0..511
    int rp = u & 31, b = u >> 5;
    int h0 = rp * 2;
    const float* xb = x + ((size_t)b * CI + cc * 32) * (H * W);
    const float* st = style + b * CI + cc * 32;
#pragma unroll
    for (int k = 0; k < 4; ++k) {
        int idx = tid + k * 256;                  // < 1024 float4s
        int w4 = idx & 15, ci = (idx >> 4) & 31, r = idx >> 9;   // r: 0..1
        f32x4 v = *(const f32x4*)(xb + ((size_t)ci * H + h0 + r) * W + w4 * 4);
        float s = st[ci];
        t[r][ci][w4 * 4 + 0] = v.x * s;
        t[r][ci][w4 * 4 + 1] = v.y * s;
        t[r][ci][w4 * 4 + 2] = v.z * s;
        t[r][ci][w4 * 4 + 3] = v.w * s;
    }
    __syncthreads();
#pragma unroll
    for (int k = 0; k < 2; ++k) {
        int q = tid + k * 256;                    // < 512 chunks
        int w = q & 63, sub = (q >> 6) & 3, r = q >> 8;          // r: 0..1
        bf16x8 v;
#pragma unroll
        for (int j = 0; j < 8; ++j) v[j] = (bf16)t[r][sub * 8 + j][w];
        xp[(((size_t)b * PH + h0 + r + 1) * 32 + cc * 4 + sub) * PH + (w + 1)] = v;
    }
    if (tid < 16) {                               // border cols for these rows
        int r = (tid >> 3) & 1, sub = (tid >> 1) & 3;
        int col = (tid & 1) ? (PH - 1) : 0;
        xp[(((size_t)b * PH + h0 + r + 1) * 32 + cc * 4 + sub) * PH + col] = z;
    }
}

// ----------------------------------------------------------------- conv ----
// VERBATIM round-4 verified 74.0us kernel: 1-deep register double-buffer +
// sched_barrier pinning + setprio(T5); (256,2); grid 512 XCD-pinned.
#define LOAD_TAP(c8_, kh_, kw_, av_, bv_)                                         \
    {                                                                             \
        const bf16x8* wq_ = wbase + ((size_t)((kh_)*3 + (kw_)) * 32 + (c8_)) * CO;\
        const bf16x8* xq_ = xbase + ((size_t)(kh_) * 32 * PH + (size_t)(c8_) * PH + (kw_)); \
        _Pragma("unroll") for (int a_ = 0; a_ < 4; ++a_) (av_)[a_] = wq_[a_ * 16];\
        _Pragma("unroll") for (int jr_ = 0; jr_ < 2; ++jr_)                       \
            _Pragma("unroll") for (int jc_ = 0; jc_ < 4; ++jc_)                   \
                (bv_)[jr_ * 4 + jc_] = xq_[(size_t)jr_ * 32 * PH + jc_ * 16];     \
    }

#define MFMA_STEP(av_, bv_)                                                       \
    __builtin_amdgcn_s_setprio(1);                                                \
    _Pragma("unroll") for (int a_ = 0; a_ < 4; ++a_)                              \
        _Pragma("unroll") for (int j_ = 0; j_ < 8; ++j_)                          \
            acc[a_][j_] = __builtin_amdgcn_mfma_f32_16x16x32_bf16(                \
                (av_)[a_], (bv_)[j_], acc[a_][j_], 0, 0, 0);                      \
    __builtin_amdgcn_s_setprio(0);

__global__ __launch_bounds__(256, 2) void conv_kernel(
                            const bf16x8* __restrict__ wd,
                            const bf16x8* __restrict__ xp,
                            const float* __restrict__ bias,
                            const float* __restrict__ invstd,
                            float* __restrict__ out) {
    int i = blockIdx.x;
    int xcd = i & 7, tq = i >> 3;              // tq: 0..63
    int b = xcd * 2 + (tq >> 5);               // 2 samples per XCD
    int rest = tq & 31;
    int cotile = rest & 1, rowquad = rest >> 1;
    int tid = threadIdx.x;
    int wave = tid >> 6, lane = tid & 63;
    int co_half = wave & 1, sp_half = wave >> 1;
    int r0 = rowquad * 4 + sp_half * 2;
    int co_base = cotile * 128 + co_half * 64;
    int lm = lane & 15, lk = lane >> 4;

    f32x4 acc[4][8] = {};

    const bf16x8* xpb = xp + (size_t)b * PH * 32 * PH;
    const bf16x8* wbase = wd + (size_t)lk * CO + co_base + lm;
    const bf16x8* xbase = xpb + ((size_t)r0 * 32 + lk) * PH + lm;

    bf16x8 av0[4], bv0[8], av1[4], bv1[8];

    LOAD_TAP(0, 0, 0, av0, bv0);

#pragma unroll 1
    for (int c8a = 0; c8a < 32; c8a += 8) {
#pragma unroll
        for (int v = 0; v < 18; ++v) {
            const int ntap = (v + 1) % 9;
            const int nkh = ntap / 3, nkw = ntap % 3;
            int nc8 = (v == 17) ? ((c8a + 8) & 31)
                                : (c8a + ((v + 1) / 9) * 4);
            if ((v & 1) == 0) {
                LOAD_TAP(nc8, nkh, nkw, av1, bv1);
                __builtin_amdgcn_sched_barrier(0);
                MFMA_STEP(av0, bv0);
            } else {
                LOAD_TAP(nc8, nkh, nkw, av0, bv0);
                __builtin_amdgcn_sched_barrier(0);
                MFMA_STEP(av1, bv1);
            }
        }
    }

#pragma unroll
    for (int a = 0; a < 4; ++a) {
#pragma unroll
        for (int g = 0; g < 4; ++g) {
            int co = co_base + a * 16 + lk * 4 + g;
            float sc = invstd[b * CO + co];
            float bvl = bias[co];
#pragma unroll
            for (int jr = 0; jr < 2; ++jr) {
                size_t o = (((size_t)b * CO + co) * H + r0 + jr) * W;
#pragma unroll
                for (int jc = 0; jc < 4; ++jc)
                    out[o + jc * 16 + lm] = acc[a][jr * 4 + jc][g] * sc + bvl;
            }
        }
    }
}

// --------------------------------------------------------------- launch ----
extern "C" void kernel_launch(void* const* d_in, const int* in_sizes, int n_in,
                              void* d_out, int out_size, void* d_ws, size_t ws_size,
                              hipStream_t stream) {
    const float* x    = (const float*)d_in[0];
    const float* y    = (const float*)d_in[1];
    const float* wts  = (const float*)d_in[2];
    const float* bias = (const float*)d_in[3];
    const float* sw   = (const float*)d_in[4];
    const float* sb   = (const float*)d_in[5];
    float* out = (float*)d_out;

    char* ws = (char*)d_ws;
    bf16x8* wd    = (bf16x8*)(ws + WS_WD);
    bf16x8* xpad  = (bf16x8*)(ws + WS_XPAD);
    float* style  = (float*)(ws + WS_STYLE);
    float* wsqT   = (float*)(ws + WS_WSQT);
    float* invstd = (float*)(ws + WS_INV);

    prep1_kernel<<<dim3(1280), dim3(256), 0, stream>>>(y, sw, sb, wts, wd, wsqT, style);
    prep2_kernel<<<dim3(4240), dim3(256), 0, stream>>>(x, style, wsqT, xpad, invstd);
    conv_kernel<<<dim3(512), dim3(256), 0, stream>>>(wd, xpad, bias, invstd, out);
}